// Round 9
// baseline (304.828 us; speedup 1.0000x reference)
//
#include <hip/hip_runtime.h>
#include <hip/hip_cooperative_groups.h>

namespace cg = cooperative_groups;

#define N_NODES 2048
#define F_IN    2048
#define G1      10
#define NCLS    10
#define NEDGE   65536
#define JCHUNKS 64
#define JPER    32                   // K-elements per chunk
#define HSLICES 128                  // histogram edge slices
#define ZSLICES 64                   // scatter edge slices per k-half
#define NBLK    512                  // 2 blocks/CU on 256 CUs (co-resident)

// Device-global intermediates (bss of the .so) — fully overwritten each call.
__device__ float g_p[JCHUNKS * 20 * N_NODES];       // [jc][k][row] split-K partials (10.5 MB)
__device__ int   g_degp[HSLICES * N_NODES];         // per-slice degree histograms (1 MB)
__device__ float g_dis[N_NODES];                    // deg>0 ? rsqrt(deg) : 0
__device__ float g_y[N_NODES * 20];                 // [row][k]: k<10 x@W0, k>=10 x@W1
__device__ float g_zp[2 * ZSLICES * N_NODES * 5];   // [khalf][slice][i*5+kk] (5.25 MB)

// One cooperative kernel, 4 phases separated by grid.sync() (replaces 3
// dispatch gaps). LDS: 40 KB union (gemm x-tile 33.8 KB / hist 8 KB /
// scatter z 40 KB / zf 1.3 KB) -> 2 blocks/CU.
__global__ __launch_bounds__(256) void k_all(const float* __restrict__ x,
                                             const float* __restrict__ W0,
                                             const float* __restrict__ W1,
                                             const int* __restrict__ ei,
                                             const float* __restrict__ b,
                                             const float* __restrict__ Wf,
                                             const float* __restrict__ bfv,
                                             float* __restrict__ out) {
    __shared__ float smem[N_NODES * 5];          // 40 KB
    cg::grid_group grid = cg::this_grid();
    int bid = blockIdx.x;
    int tid = threadIdx.x;

    // ---- Phase A: split-K GEMM (LDS-staged coalesced x) + degree histogram ----
    {
        int jc      = bid & 63;                  // K-chunk 0..63
        int by      = bid >> 6;                  // row-tile 0..7
        int rowbase = by * 256;
        int j0      = jc * JPER;
        float* sx   = smem;                      // 256 x 33 floats

        #pragma unroll
        for (int rep = 0; rep < 8; ++rep) {
            int idx = rep * 256 + tid;
            int r = idx >> 3, c4 = idx & 7;
            float4 v = *(const float4*)(x + (size_t)(rowbase + r) * F_IN + j0 + c4 * 4);
            float* d = sx + r * 33 + c4 * 4;
            d[0] = v.x; d[1] = v.y; d[2] = v.z; d[3] = v.w;
        }
        __syncthreads();

        float acc[20];
        #pragma unroll
        for (int k = 0; k < 20; ++k) acc[k] = 0.f;

        const float* xr = sx + tid * 33;
        #pragma unroll
        for (int j = 0; j < JPER; ++j) {
            float xu = xr[j];
            const float* w0r = W0 + (size_t)(j0 + j) * G1;   // uniform -> s_load
            const float* w1r = W1 + (size_t)(j0 + j) * G1;
            #pragma unroll
            for (int k = 0; k < G1; ++k) {
                acc[k]      += xu * w0r[k];
                acc[10 + k] += xu * w1r[k];
            }
        }
        int row = rowbase + tid;
        #pragma unroll
        for (int k = 0; k < 20; ++k)
            g_p[((size_t)jc * 20 + k) * N_NODES + row] = acc[k];   // coalesced

        // degree histogram on 128 blocks (by<4 && jc<32), 512 edges each
        if (by < 4 && jc < 32) {
            int slice = by * 32 + jc;            // 0..127
            __syncthreads();                     // x-tile reads done; reuse LDS
            int* h = (int*)smem;
            for (int t = tid; t < N_NODES; t += 256) h[t] = 0;
            __syncthreads();
            int base = slice * (NEDGE / HSLICES);
            #pragma unroll
            for (int u = 0; u < 2; ++u)
                atomicAdd(&h[ei[base + u * 256 + tid]], 1);
            __syncthreads();
            for (int t = tid; t < N_NODES; t += 256)
                g_degp[slice * N_NODES + t] = h[t];
        }
    }
    grid.sync();

    // ---- Phase B: reduce GEMM partials -> g_y ; degree partials -> g_dis ----
    {
        int t = bid * 256 + tid;                 // blocks 0..159 carry the work
        if (t < N_NODES * 20) {
            int k   = t >> 11;
            int row = t & (N_NODES - 1);
            float s = 0.f;
            #pragma unroll 16
            for (int jc = 0; jc < JCHUNKS; ++jc)
                s += g_p[((size_t)jc * 20 + k) * N_NODES + row];
            g_y[row * 20 + k] = s;
        }
        if (t < N_NODES) {
            int d = 0;
            #pragma unroll 16
            for (int sl = 0; sl < HSLICES; ++sl) d += g_degp[sl * N_NODES + t];
            g_dis[t] = (d > 0) ? rsqrtf((float)d) : 0.f;
        }
    }
    grid.sync();

    // ---- Phase C: edge scatter in projected space, blocks 0..127 ----
    if (bid < 2 * ZSLICES) {
        int khalf  = bid >> 6;
        int bslice = bid & (ZSLICES - 1);
        float4* zl4 = (float4*)smem;
        #pragma unroll
        for (int t = tid; t < N_NODES * 5 / 4; t += 256)
            zl4[t] = make_float4(0.f, 0.f, 0.f, 0.f);
        __syncthreads();
        int base = bslice * (NEDGE / ZSLICES);
        #pragma unroll
        for (int u = 0; u < NEDGE / ZSLICES / 256; ++u) {
            int e = base + u * 256 + tid;
            int r = ei[e], c = ei[NEDGE + e];
            float w = -g_dis[r] * g_dis[c];      // 0 if either deg==0
            const float* y1 = g_y + r * 20 + 10 + khalf * 5;
            float* zz = smem + c * 5;
            #pragma unroll
            for (int kk = 0; kk < 5; ++kk) atomicAdd(&zz[kk], w * y1[kk]);
        }
        __syncthreads();
        float4* dst = (float4*)(g_zp + ((size_t)khalf * ZSLICES + bslice) * (N_NODES * 5));
        #pragma unroll
        for (int t = tid; t < N_NODES * 5 / 4; t += 256) dst[t] = zl4[t];
    }
    grid.sync();

    // ---- Phase D: z-reduction + epilogue, blocks 0..63 x 32 nodes ----
    if (bid < 64) {
        float* zb = smem;                        // 320 floats
        int nb = bid * 32;
        for (int v = tid; v < 320; v += 256) {
            int khalf = v / 160;
            int rem   = v - khalf * 160;
            int il    = rem / 5, kk = rem - il * 5;
            float s = 0.f;
            #pragma unroll 16
            for (int sl = 0; sl < ZSLICES; ++sl)
                s += g_zp[((size_t)khalf * ZSLICES + sl) * (N_NODES * 5) + (nb + il) * 5 + kk];
            zb[il * 10 + khalf * 5 + kk] = s;
        }
        __syncthreads();
        if (tid < 32) {
            int i = nb + tid;
            float h[G1];
            #pragma unroll
            for (int k = 0; k < G1; ++k)
                h[k] = fmaxf(g_y[i * 20 + k] + zb[tid * 10 + k] + b[k], 0.f);
            float lo[NCLS];
            #pragma unroll
            for (int c = 0; c < NCLS; ++c) lo[c] = bfv[c];
            #pragma unroll
            for (int k = 0; k < G1; ++k) {
                float hk = h[k];
                #pragma unroll
                for (int c = 0; c < NCLS; ++c) lo[c] += hk * Wf[k * NCLS + c];
            }
            float m = lo[0];
            #pragma unroll
            for (int c = 1; c < NCLS; ++c) m = fmaxf(m, lo[c]);
            float s = 0.f;
            #pragma unroll
            for (int c = 0; c < NCLS; ++c) s += expf(lo[c] - m);
            float ls = logf(s);
            #pragma unroll
            for (int c = 0; c < NCLS; ++c) out[i * NCLS + c] = lo[c] - m - ls;
        }
    }
}

extern "C" void kernel_launch(void* const* d_in, const int* in_sizes, int n_in,
                              void* d_out, int out_size, void* d_ws, size_t ws_size,
                              hipStream_t stream) {
    const float* x   = (const float*)d_in[0];
    const int*   ei  = (const int*)d_in[1];
    const float* W0  = (const float*)d_in[2];
    const float* W1  = (const float*)d_in[3];
    const float* b   = (const float*)d_in[4];
    const float* Wf  = (const float*)d_in[5];
    const float* bfv = (const float*)d_in[6];
    float* out = (float*)d_out;

    void* args[] = {(void*)&x, (void*)&ei, (void*)&W0, (void*)&W1,
                    (void*)&b, (void*)&Wf, (void*)&bfv, (void*)&out};
    // arg order must match kernel params: x, W0, W1, ei, b, Wf, bfv, out
    void* args2[] = {(void*)&x, (void*)&W0, (void*)&W1, (void*)&ei,
                     (void*)&b, (void*)&Wf, (void*)&bfv, (void*)&out};
    hipLaunchCooperativeKernel((void*)k_all, dim3(NBLK), dim3(256),
                               args2, 0, stream);
}

// Round 10
// 112.707 us; speedup vs baseline: 2.7046x; 2.7046x over previous
//
#include <hip/hip_runtime.h>

#define N_NODES 2048
#define F_IN    2048
#define G1      10
#define NCLS    10
#define NEDGE   65536
#define JCHUNKS 32
#define JPER    64                   // K-elements per chunk (64 cols, 2 thread-halves)
#define RTILE   128                  // rows per block
#define HSLICES 128                  // histogram edge slices (fused into k_gemm)
#define ZSLICES 64                   // scatter edge slices per k-half

// Device-global intermediates (bss of the .so) — fully overwritten each call.
__device__ float g_p[JCHUNKS * 20 * N_NODES];       // [jc][k][row] split-K partials (5.25 MB)
__device__ int   g_degp[HSLICES * N_NODES];         // per-slice degree histograms (1 MB)
__device__ float g_dis[N_NODES];                    // deg>0 ? rsqrt(deg) : 0
__device__ float g_y[N_NODES * 20];                 // [row][k]: k<10 x@W0, k>=10 x@W1
__device__ float g_zp[2 * ZSLICES * N_NODES * 5];   // [khalf][slice][i*5+kk] (5.25 MB)

// ---- 1) split-K GEMM + fused degree histogram ----
// Grid (32,16) = 512 blocks = 2/CU. Block: 128 rows x 64 cols; thread =
// (h = tid>>7, r = tid&127) -> h and the j-loop are wave-uniform so W rows
// stay s_load broadcasts. Col-halves combine in-block via LDS (stride 21 ->
// 2 lanes/bank, free), halving g_p traffic vs 64-chunk split-K.
__global__ __launch_bounds__(256) void k_gemm(const float* __restrict__ x,
                                              const float* __restrict__ W0,
                                              const float* __restrict__ W1,
                                              const int* __restrict__ ei) {
    __shared__ float sx[RTILE * 65];             // 33.3 KB
    int jc      = blockIdx.x;                    // 0..31
    int rowbase = blockIdx.y * RTILE;
    int j0      = jc * JPER;

    // stage 128 rows x 64 cols, coalesced float4
    #pragma unroll
    for (int rep = 0; rep < 8; ++rep) {
        int idx = rep * 256 + threadIdx.x;       // 0..2047
        int r = idx >> 4, c4 = idx & 15;
        float4 v = *(const float4*)(x + (size_t)(rowbase + r) * F_IN + j0 + c4 * 4);
        float* d = sx + r * 65 + c4 * 4;
        d[0] = v.x; d[1] = v.y; d[2] = v.z; d[3] = v.w;
    }
    __syncthreads();

    int h = threadIdx.x >> 7;                    // col-half, wave-uniform
    int r = threadIdx.x & 127;                   // row in tile
    float acc[20];
    #pragma unroll
    for (int k = 0; k < 20; ++k) acc[k] = 0.f;

    const float* xr = sx + r * 65 + h * 32;
    #pragma unroll
    for (int j = 0; j < 32; ++j) {
        float xu = xr[j];
        int jcol = j0 + h * 32 + j;              // wave-uniform
        const float* w0r = W0 + (size_t)jcol * G1;   // -> s_load
        const float* w1r = W1 + (size_t)jcol * G1;
        #pragma unroll
        for (int k = 0; k < G1; ++k) {
            acc[k]      += xu * w0r[k];
            acc[10 + k] += xu * w1r[k];
        }
    }
    __syncthreads();                             // sx reads done; reuse LDS
    float* red = sx;                             // 128 x 21 floats (10.5 KB)
    if (h == 1) {
        #pragma unroll
        for (int k = 0; k < 20; ++k) red[r * 21 + k] = acc[k];
    }
    __syncthreads();
    if (h == 0) {
        int row = rowbase + r;
        #pragma unroll
        for (int k = 0; k < 20; ++k)
            g_p[((size_t)jc * 20 + k) * N_NODES + row] = acc[k] + red[r * 21 + k];
    }

    // fused degree histogram: 128 of 512 blocks, 512 edges each
    if (blockIdx.y < 8 && jc < 16) {
        int slice = blockIdx.y * 16 + jc;        // 0..127
        __syncthreads();
        int* hh = (int*)sx;
        for (int t = threadIdx.x; t < N_NODES; t += 256) hh[t] = 0;
        __syncthreads();
        int base = slice * (NEDGE / HSLICES);    // 512 edges per slice
        #pragma unroll
        for (int u = 0; u < 2; ++u)
            atomicAdd(&hh[ei[base + u * 256 + threadIdx.x]], 1);
        __syncthreads();
        for (int t = threadIdx.x; t < N_NODES; t += 256)
            g_degp[slice * N_NODES + t] = hh[t];
    }
}

// ---- 2) reduce GEMM partials -> g_y ; degree partials -> g_dis ----
__global__ __launch_bounds__(256) void k_reduce() {
    int t   = blockIdx.x * 256 + threadIdx.x;   // 160 blocks -> t < 40960
    int k   = t >> 11;
    int row = t & (N_NODES - 1);
    float s = 0.f;
    #pragma unroll 16
    for (int jc = 0; jc < JCHUNKS; ++jc)
        s += g_p[((size_t)jc * 20 + k) * N_NODES + row];
    g_y[row * 20 + k] = s;
    if (t < N_NODES) {
        int d = 0;
        #pragma unroll 16
        for (int sl = 0; sl < HSLICES; ++sl) d += g_degp[sl * N_NODES + t];
        g_dis[t] = (d > 0) ? rsqrtf((float)d) : 0.f;
    }
}

// ---- 3) edge scatter in projected space, LDS-privatized ----
// 128 blocks: khalf = bx>>6 (k in [khalf*5,khalf*5+5)), slice = bx&63 (1024 edges).
__global__ __launch_bounds__(256) void k_scatter(const int* __restrict__ ei) {
    __shared__ float zl[N_NODES * 5];            // 40 KB
    int khalf  = blockIdx.x >> 6;
    int bslice = blockIdx.x & (ZSLICES - 1);
    float4* zl4 = (float4*)zl;
    #pragma unroll
    for (int t = threadIdx.x; t < N_NODES * 5 / 4; t += 256)
        zl4[t] = make_float4(0.f, 0.f, 0.f, 0.f);
    __syncthreads();
    int base = bslice * (NEDGE / ZSLICES);
    #pragma unroll
    for (int u = 0; u < NEDGE / ZSLICES / 256; ++u) {
        int e = base + u * 256 + threadIdx.x;
        int r = ei[e], c = ei[NEDGE + e];
        float w = -g_dis[r] * g_dis[c];          // 0 if either deg==0
        const float* y1 = g_y + r * 20 + 10 + khalf * 5;
        float* zz = zl + c * 5;
        #pragma unroll
        for (int kk = 0; kk < 5; ++kk) atomicAdd(&zz[kk], w * y1[kk]);
    }
    __syncthreads();
    float4* dst = (float4*)(g_zp + ((size_t)khalf * ZSLICES + bslice) * (N_NODES * 5));
    #pragma unroll
    for (int t = threadIdx.x; t < N_NODES * 5 / 4; t += 256) dst[t] = zl4[t];
}

// ---- 4) fused z-reduction + epilogue, 64 blocks x 32 nodes ----
__global__ __launch_bounds__(256) void k_zf(const float* __restrict__ b,
                                            const float* __restrict__ Wf,
                                            const float* __restrict__ bfv,
                                            float* __restrict__ out) {
    __shared__ float zb[320];                    // [il][k] for 32 nodes
    int nb = blockIdx.x * 32;
    for (int v = threadIdx.x; v < 320; v += 256) {
        int khalf = v / 160;
        int rem   = v - khalf * 160;             // il*5 + kk
        int il    = rem / 5, kk = rem - il * 5;
        float s = 0.f;
        #pragma unroll 16
        for (int sl = 0; sl < ZSLICES; ++sl)
            s += g_zp[((size_t)khalf * ZSLICES + sl) * (N_NODES * 5) + (nb + il) * 5 + kk];
        zb[il * 10 + khalf * 5 + kk] = s;
    }
    __syncthreads();
    if (threadIdx.x < 32) {
        int i = nb + threadIdx.x;
        float h[G1];
        #pragma unroll
        for (int k = 0; k < G1; ++k)
            h[k] = fmaxf(g_y[i * 20 + k] + zb[threadIdx.x * 10 + k] + b[k], 0.f);
        float lo[NCLS];
        #pragma unroll
        for (int c = 0; c < NCLS; ++c) lo[c] = bfv[c];
        #pragma unroll
        for (int k = 0; k < G1; ++k) {
            float hk = h[k];
            #pragma unroll
            for (int c = 0; c < NCLS; ++c) lo[c] += hk * Wf[k * NCLS + c];
        }
        float m = lo[0];
        #pragma unroll
        for (int c = 1; c < NCLS; ++c) m = fmaxf(m, lo[c]);
        float s = 0.f;
        #pragma unroll
        for (int c = 0; c < NCLS; ++c) s += expf(lo[c] - m);
        float ls = logf(s);
        #pragma unroll
        for (int c = 0; c < NCLS; ++c) out[i * NCLS + c] = lo[c] - m - ls;
    }
}

extern "C" void kernel_launch(void* const* d_in, const int* in_sizes, int n_in,
                              void* d_out, int out_size, void* d_ws, size_t ws_size,
                              hipStream_t stream) {
    const float* x   = (const float*)d_in[0];
    const int*   ei  = (const int*)d_in[1];
    const float* W0  = (const float*)d_in[2];
    const float* W1  = (const float*)d_in[3];
    const float* b   = (const float*)d_in[4];
    const float* Wf  = (const float*)d_in[5];
    const float* bfv = (const float*)d_in[6];
    float* out = (float*)d_out;

    k_gemm<<<dim3(JCHUNKS, N_NODES / RTILE), 256, 0, stream>>>(x, W0, W1, ei);
    k_reduce<<<(N_NODES * 20) / 256, 256, 0, stream>>>();
    k_scatter<<<2 * ZSLICES, 256, 0, stream>>>(ei);
    k_zf<<<N_NODES / 32, 256, 0, stream>>>(b, Wf, bfv, out);
}

// Round 11
// 111.100 us; speedup vs baseline: 2.7437x; 1.0145x over previous
//
#include <hip/hip_runtime.h>

#define N_NODES 2048
#define F_IN    2048
#define G1      10
#define NCLS    10
#define NEDGE   65536
#define JCHUNKS 64
#define JPER    32                   // K-elements per chunk
#define HSLICES 128                  // histogram edge slices (fused into k_gemm)
#define ZSLICES 64                   // scatter edge slices per k-half

// Device-global intermediates (bss of the .so) — fully overwritten each call.
// Empirical best configuration (R6: 110.8 us). Partial-buffer sizes are
// performance-neutral (L2/L3-absorbed — R8/R10 A/B tests); dispatch count
// 5 vs 4 is within noise; cooperative single-dispatch regresses 3x (R9).
__device__ float g_p[JCHUNKS * 20 * N_NODES];       // [jc][k][row] split-K partials (10.5 MB)
__device__ int   g_degp[HSLICES * N_NODES];         // per-slice degree histograms (1 MB)
__device__ float g_dis[N_NODES];                    // deg>0 ? rsqrt(deg) : 0
__device__ float g_y[N_NODES * 20];                 // [row][k]: k<10 x@W0, k>=10 x@W1
__device__ float g_zp[2 * ZSLICES * N_NODES * 5];   // [khalf][slice][i*5+kk] (5.25 MB)
__device__ float g_z[N_NODES * G1];                 // reduced Tx1@W1 scatter

// ---- 1) split-K GEMM (LDS-staged coalesced x) + fused degree histogram ----
// Grid (64,8) = 512 blocks = 2/CU. Tile 256 rows x 32 cols, LDS stride 33 ->
// 2 lanes/bank (free). j loop-uniform -> W rows via s_load broadcast.
__global__ __launch_bounds__(256) void k_gemm(const float* __restrict__ x,
                                              const float* __restrict__ W0,
                                              const float* __restrict__ W1,
                                              const int* __restrict__ ei) {
    __shared__ float sx[256 * 33];   // 33.8 KB
    int jc      = blockIdx.x;        // 0..63
    int rowbase = blockIdx.y * 256;
    int j0      = jc * JPER;

    #pragma unroll
    for (int rep = 0; rep < 8; ++rep) {
        int idx = rep * 256 + threadIdx.x;
        int r = idx >> 3, c4 = idx & 7;
        float4 v = *(const float4*)(x + (size_t)(rowbase + r) * F_IN + j0 + c4 * 4);
        float* d = sx + r * 33 + c4 * 4;
        d[0] = v.x; d[1] = v.y; d[2] = v.z; d[3] = v.w;
    }
    __syncthreads();

    float acc[20];
    #pragma unroll
    for (int k = 0; k < 20; ++k) acc[k] = 0.f;

    const float* xr = sx + threadIdx.x * 33;
    #pragma unroll
    for (int j = 0; j < JPER; ++j) {
        float xu = xr[j];
        const float* w0r = W0 + (size_t)(j0 + j) * G1;  // uniform -> s_load
        const float* w1r = W1 + (size_t)(j0 + j) * G1;
        #pragma unroll
        for (int k = 0; k < G1; ++k) {
            acc[k]      += xu * w0r[k];
            acc[10 + k] += xu * w1r[k];
        }
    }
    int row = rowbase + threadIdx.x;
    #pragma unroll
    for (int k = 0; k < 20; ++k)
        g_p[((size_t)jc * 20 + k) * N_NODES + row] = acc[k];   // coalesced

    // fused degree histogram: 128 of 512 blocks, 512 edges each
    if (blockIdx.y < 4 && jc < 32) {
        int slice = blockIdx.y * 32 + jc;        // 0..127
        __syncthreads();
        int* h = (int*)sx;
        for (int t = threadIdx.x; t < N_NODES; t += 256) h[t] = 0;
        __syncthreads();
        int base = slice * (NEDGE / HSLICES);    // 512 edges per slice
        #pragma unroll
        for (int u = 0; u < 2; ++u)
            atomicAdd(&h[ei[base + u * 256 + threadIdx.x]], 1);
        __syncthreads();
        for (int t = threadIdx.x; t < N_NODES; t += 256)
            g_degp[slice * N_NODES + t] = h[t];
    }
}

// ---- 2) reduce GEMM partials -> g_y ; degree partials -> g_dis ----
__global__ __launch_bounds__(256) void k_reduce() {
    int t   = blockIdx.x * 256 + threadIdx.x;   // 160 blocks -> t < 40960
    int k   = t >> 11;
    int row = t & (N_NODES - 1);
    float s = 0.f;
    #pragma unroll 16
    for (int jc = 0; jc < JCHUNKS; ++jc)
        s += g_p[((size_t)jc * 20 + k) * N_NODES + row];
    g_y[row * 20 + k] = s;
    if (t < N_NODES) {
        int d = 0;
        #pragma unroll 16
        for (int sl = 0; sl < HSLICES; ++sl) d += g_degp[sl * N_NODES + t];
        g_dis[t] = (d > 0) ? rsqrtf((float)d) : 0.f;
    }
}

// ---- 3) edge scatter in projected space, LDS-privatized ----
// 128 blocks: khalf = bx>>6 (k in [khalf*5,khalf*5+5)), slice = bx&63 (1024 edges).
__global__ __launch_bounds__(256) void k_scatter(const int* __restrict__ ei) {
    __shared__ float zl[N_NODES * 5];            // 40 KB
    int khalf  = blockIdx.x >> 6;
    int bslice = blockIdx.x & (ZSLICES - 1);
    float4* zl4 = (float4*)zl;
    #pragma unroll
    for (int t = threadIdx.x; t < N_NODES * 5 / 4; t += 256)
        zl4[t] = make_float4(0.f, 0.f, 0.f, 0.f);
    __syncthreads();
    int base = bslice * (NEDGE / ZSLICES);
    #pragma unroll
    for (int u = 0; u < NEDGE / ZSLICES / 256; ++u) {
        int e = base + u * 256 + threadIdx.x;
        int r = ei[e], c = ei[NEDGE + e];
        float w = -g_dis[r] * g_dis[c];          // 0 if either deg==0
        const float* y1 = g_y + r * 20 + 10 + khalf * 5;
        float* zz = zl + c * 5;
        #pragma unroll
        for (int kk = 0; kk < 5; ++kk) atomicAdd(&zz[kk], w * y1[kk]);
    }
    __syncthreads();
    float4* dst = (float4*)(g_zp + ((size_t)khalf * ZSLICES + bslice) * (N_NODES * 5));
    #pragma unroll
    for (int t = threadIdx.x; t < N_NODES * 5 / 4; t += 256) dst[t] = zl4[t];
}

// ---- 4) coalesced z-partial reduction -> g_z[node][k] ----
__global__ __launch_bounds__(256) void k_zred() {
    int t = blockIdx.x * 256 + threadIdx.x;      // 80 blocks -> t < 20480
    int khalf = t / (N_NODES * 5);
    int rem   = t % (N_NODES * 5);
    float s = 0.f;
    #pragma unroll 16
    for (int sl = 0; sl < ZSLICES; ++sl)
        s += g_zp[((size_t)khalf * ZSLICES + sl) * (N_NODES * 5) + rem];
    int i = rem / 5, kk = rem - i * 5;
    g_z[i * 10 + khalf * 5 + kk] = s;
}

// ---- 5) epilogue: relu(y0+z+b) @ Wf + log_softmax ----
__global__ __launch_bounds__(256) void k_final(const float* __restrict__ b,
                                               const float* __restrict__ Wf,
                                               const float* __restrict__ bfv,
                                               float* __restrict__ out) {
    int i = blockIdx.x * 256 + threadIdx.x;      // grid == N_NODES exactly
    float h[G1];
    #pragma unroll
    for (int k = 0; k < G1; ++k)
        h[k] = fmaxf(g_y[i * 20 + k] + g_z[i * 10 + k] + b[k], 0.f);
    float lo[NCLS];
    #pragma unroll
    for (int c = 0; c < NCLS; ++c) lo[c] = bfv[c];
    #pragma unroll
    for (int k = 0; k < G1; ++k) {
        float hk = h[k];
        #pragma unroll
        for (int c = 0; c < NCLS; ++c) lo[c] += hk * Wf[k * NCLS + c];
    }
    float m = lo[0];
    #pragma unroll
    for (int c = 1; c < NCLS; ++c) m = fmaxf(m, lo[c]);
    float s = 0.f;
    #pragma unroll
    for (int c = 0; c < NCLS; ++c) s += expf(lo[c] - m);
    float ls = logf(s);
    #pragma unroll
    for (int c = 0; c < NCLS; ++c) out[i * NCLS + c] = lo[c] - m - ls;
}

extern "C" void kernel_launch(void* const* d_in, const int* in_sizes, int n_in,
                              void* d_out, int out_size, void* d_ws, size_t ws_size,
                              hipStream_t stream) {
    const float* x   = (const float*)d_in[0];
    const int*   ei  = (const int*)d_in[1];
    const float* W0  = (const float*)d_in[2];
    const float* W1  = (const float*)d_in[3];
    const float* b   = (const float*)d_in[4];
    const float* Wf  = (const float*)d_in[5];
    const float* bfv = (const float*)d_in[6];
    float* out = (float*)d_out;

    k_gemm<<<dim3(JCHUNKS, N_NODES / 256), 256, 0, stream>>>(x, W0, W1, ei);
    k_reduce<<<(N_NODES * 20) / 256, 256, 0, stream>>>();
    k_scatter<<<2 * ZSLICES, 256, 0, stream>>>(ei);
    k_zred<<<(N_NODES * G1) / 256, 256, 0, stream>>>();
    k_final<<<N_NODES / 256, 256, 0, stream>>>(b, Wf, bfv, out);
}